// Round 7
// baseline (93.022 us; speedup 1.0000x reference)
//
#include <hip/hip_runtime.h>
#include <hip/hip_bf16.h>

typedef short short8 __attribute__((ext_vector_type(8)));
typedef short short4v __attribute__((ext_vector_type(4)));
typedef float float4v __attribute__((ext_vector_type(4)));
typedef float f32x4 __attribute__((ext_vector_type(4)));

#define NEG_HUGE (-1e30f)
#define QK_SCALE 0.1803368801111204f  /* 0.125 * log2(e) */

__device__ __forceinline__ unsigned short f2bf(float f) {
  union { __hip_bfloat16 h; unsigned short u; } c;
  c.h = __float2bfloat16(f);
  return c.u;
}

#define MFMA16(a, b, c) __builtin_amdgcn_mfma_f32_16x16x32_bf16((a), (b), (c), 0, 0, 0)

// ---------------------------------------------------------------------------
// Kernel 0: W [1024][64] fp32 (x3) -> Wt [3][64][1024] bf16 (transposed).
// Wq additionally scaled by 0.125*log2(e) so attn works in exp2 domain.
// ---------------------------------------------------------------------------
__global__ __launch_bounds__(256) void wtrans_kernel(
    const float* __restrict__ Wk, const float* __restrict__ Wq,
    const float* __restrict__ Wv, unsigned short* __restrict__ Wt) {
  int mat = blockIdx.x >> 4, kb = blockIdx.x & 15;
  const float* W = (mat == 0) ? Wk : ((mat == 1) ? Wq : Wv);
  float qscale = (mat == 1) ? QK_SCALE : 1.0f;
  __shared__ float tile[64][65];
  int tid = threadIdx.x;
  int n = tid & 63, k0 = tid >> 6;
#pragma unroll
  for (int i = 0; i < 16; i++) {
    int k = i * 4 + k0;
    tile[k][n] = W[(kb * 64 + k) * 64 + n];
  }
  __syncthreads();
  int n2 = tid >> 2, c = tid & 3;
  unsigned short tmp[16];
#pragma unroll
  for (int j = 0; j < 16; j++) tmp[j] = f2bf(tile[c * 16 + j][n2] * qscale);
  unsigned short* dst = Wt + (mat * 64 + n2) * 1024 + kb * 64 + c * 16;
  *(short8*)dst = *(short8*)tmp;
  *(short8*)(dst + 8) = *(short8*)(tmp + 8);
}

// ---------------------------------------------------------------------------
// Kernel 1: projection. x[16384][1024] fp32 @ Wt[3][64][1024] bf16
//   -> Kb/Qb [16384][64] bf16 (row-major),
//      Vt [4][64][4096] bf16 transposed with per-64-block kv permutation
//      sigma(kv) = (nf>>1)*32 + g*8 + (nf&1)*4 + reg  (nf=(kv>>4)&3,
//      g=(kv>>2)&3, reg=kv&3) so attn PV B-fragments are lane-local.
// ---------------------------------------------------------------------------
__global__ __launch_bounds__(256, 4) void proj_kernel(
    const float* __restrict__ x, const unsigned short* __restrict__ Wt,
    unsigned short* __restrict__ Kb, unsigned short* __restrict__ Qb,
    unsigned short* __restrict__ Vt) {
  __shared__ unsigned short x_lds[32][40];
  __shared__ unsigned short w_lds[192][40];
  int tid = threadIdx.x;
  int w = tid >> 6, lane = tid & 63;
  int wm = w & 1, wn = w >> 1;
  int g = lane >> 4, r = lane & 15;
  int row0 = blockIdx.x * 32;

  int xr = tid >> 3, c4 = tid & 7;
  const float* xp = &x[(size_t)(row0 + xr) * 1024 + c4 * 4];

  f32x4 acc[6];
#pragma unroll
  for (int nf = 0; nf < 6; nf++) acc[nf] = (f32x4){0.f, 0.f, 0.f, 0.f};

  float4v xv = *(const float4v*)xp;
  short8 wv[3];
#pragma unroll
  for (int i = 0; i < 3; i++) {
    int idx = tid + i * 256;
    int wr = idx >> 2, c = idx & 3;
    wv[i] = *(const short8*)&Wt[wr * 1024 + c * 8];
  }

  for (int k0 = 0; k0 < 1024; k0 += 32) {
    {
      unsigned short t4[4];
      t4[0] = f2bf(xv[0]); t4[1] = f2bf(xv[1]); t4[2] = f2bf(xv[2]); t4[3] = f2bf(xv[3]);
      *(short4v*)&x_lds[xr][c4 * 4] = *(short4v*)t4;
    }
#pragma unroll
    for (int i = 0; i < 3; i++) {
      int idx = tid + i * 256;
      int wr = idx >> 2, c = idx & 3;
      *(short8*)&w_lds[wr][c * 8] = wv[i];
    }
    if (k0 + 32 < 1024) {
      xv = *(const float4v*)(xp + k0 + 32);
#pragma unroll
      for (int i = 0; i < 3; i++) {
        int idx = tid + i * 256;
        int wr = idx >> 2, c = idx & 3;
        wv[i] = *(const short8*)&Wt[wr * 1024 + k0 + 32 + c * 8];
      }
    }
    __syncthreads();
    short8 a = *(short8*)&x_lds[wm * 16 + r][g * 8];
#pragma unroll
    for (int nf = 0; nf < 6; nf++) {
      short8 bf = *(short8*)&w_lds[wn * 96 + nf * 16 + r][g * 8];
      acc[nf] = MFMA16(a, bf, acc[nf]);
    }
    __syncthreads();
  }
#pragma unroll
  for (int nf = 0; nf < 6; nf++) {
    int col = wn * 96 + nf * 16 + r;
    if (col < 128) {
      int mat = col >> 6, h = col & 63;
      unsigned short* dst = (mat == 0) ? Kb : Qb;
#pragma unroll
      for (int reg = 0; reg < 4; reg++) {
        int grow = row0 + wm * 16 + g * 4 + reg;
        dst[(size_t)grow * 64 + h] = f2bf(acc[nf][reg]);
      }
    } else {
      int h = col & 63;
      int grow0 = row0 + wm * 16 + g * 4;
      unsigned short t4[4];
#pragma unroll
      for (int reg = 0; reg < 4; reg++) t4[reg] = f2bf(acc[nf][reg]);
      // sigma permutation within the 64-row block (reg stays contiguous)
      int kv6 = grow0 & 63;
      int nfb = (kv6 >> 4) & 3, gb = (kv6 >> 2) & 3;
      int s0 = (nfb >> 1) * 32 + gb * 8 + (nfb & 1) * 4;
      size_t off = ((size_t)(grow0 >> 12) * 64 + h) * 4096 +
                   ((size_t)(grow0 & 4095) & ~(size_t)63) + s0;
      *(short4v*)&Vt[off] = *(short4v*)t4;
    }
  }
}

// ---------------------------------------------------------------------------
// Kernel 2: causal flash attention v7.
// grid 256 = 1 block/CU, 512 thr = 8 waves (wq in 0..1 q-halves x wkv in 0..3
// kv-split). Each block processes TWO q-tiles sequentially: qtA = 64+iq
// (heavy), qtB = 63-iq (light); ntiles_A + ntiles_B = 65 for all iq -> every
// block has identical work (scheduler-independent balance).
// Swapped QK^T and swapped PV with pi-permuted V; P in registers (cvt_pk).
// No LDS/barriers in kv loop. o[nfh][reg] = O[q=wq*16+r][h=nfh*16+g*4+reg].
// ---------------------------------------------------------------------------
__global__ __launch_bounds__(512, 2) void attn_kernel(
    const unsigned short* __restrict__ Kb, const unsigned short* __restrict__ Qb,
    const unsigned short* __restrict__ VtB, float* __restrict__ out) {
  __shared__ float O_l[4][32][68];
  __shared__ float st_l[4][32][2];
  int tid = threadIdx.x;
  int w = tid >> 6, lane = tid & 63;
  int wq = w >> 2, wkv = w & 3;
  int g = lane >> 4, r = lane & 15;
  int bi = blockIdx.x;
  int b = bi & 3, iq = bi >> 2;          // iq 0..63
  const unsigned short* Kp = Kb + (size_t)b * 4096 * 64;
  const unsigned short* Qp = Qb + (size_t)b * 4096 * 64;
  const unsigned short* Vp = VtB + (size_t)b * 64 * 4096;

  for (int qi = 0; qi < 2; qi++) {
    int qt = qi ? (63 - iq) : (64 + iq);
    int qabs = qt * 32;

    // Q B-operand frags for this wave's q-half: B[q=wq*16+r][k=ks*32+g*8+j]
    short8 qa[2];
#pragma unroll
    for (int ks = 0; ks < 2; ks++)
      qa[ks] = *(const short8*)&Qp[(size_t)(qabs + wq * 16 + r) * 64 + ks * 32 + g * 8];

    float m_st = NEG_HUGE, l_ln = 0.f;
    f32x4 o[4];
#pragma unroll
    for (int nfh = 0; nfh < 4; nfh++) o[nfh] = (f32x4){0.f, 0.f, 0.f, 0.f};

    int ntiles = (qabs >> 6) + 1;
    for (int t = wkv; t < ntiles; t += 4) {
      int kvb = t << 6;
      // ---- all global frags up front ----
      short8 vf[2][4], kf[2][4];
#pragma unroll
      for (int ks = 0; ks < 2; ks++)
#pragma unroll
        for (int nfh = 0; nfh < 4; nfh++)
          vf[ks][nfh] = *(const short8*)&Vp[(size_t)(nfh * 16 + r) * 4096 + kvb + ks * 32 + g * 8];
#pragma unroll
      for (int ks = 0; ks < 2; ks++)
#pragma unroll
        for (int nf = 0; nf < 4; nf++)
          kf[ks][nf] = *(const short8*)&Kp[(size_t)(kvb + nf * 16 + r) * 64 + ks * 32 + g * 8];
      // ---- S^T = K Q^T ----
      f32x4 s[4];
#pragma unroll
      for (int nf = 0; nf < 4; nf++) s[nf] = (f32x4){0.f, 0.f, 0.f, 0.f};
      __builtin_amdgcn_s_setprio(1);
#pragma unroll
      for (int ks = 0; ks < 2; ks++)
#pragma unroll
        for (int nf = 0; nf < 4; nf++)
          s[nf] = MFMA16(kf[ks][nf], qa[ks], s[nf]);
      __builtin_amdgcn_s_setprio(0);
      // ---- causal mask (final tile only) ----
      if (kvb + 63 > qabs) {
        int q = qabs + wq * 16 + r;
#pragma unroll
        for (int nf = 0; nf < 4; nf++)
#pragma unroll
          for (int reg = 0; reg < 4; reg++) {
            int kv = kvb + nf * 16 + g * 4 + reg;
            if (kv > q) s[nf][reg] = NEG_HUGE;
          }
      }
      // ---- row max (15 in-lane fmax + xor16 + xor32) ----
      float m0 = fmaxf(fmaxf(fmaxf(s[0][0], s[0][1]), fmaxf(s[0][2], s[0][3])),
                       fmaxf(fmaxf(s[1][0], s[1][1]), fmaxf(s[1][2], s[1][3])));
      float m1 = fmaxf(fmaxf(fmaxf(s[2][0], s[2][1]), fmaxf(s[2][2], s[2][3])),
                       fmaxf(fmaxf(s[3][0], s[3][1]), fmaxf(s[3][2], s[3][3])));
      float m0a = fmaxf(m0, m1);
      m0a = fmaxf(m0a, __shfl_xor(m0a, 16));
      m0a = fmaxf(m0a, __shfl_xor(m0a, 32));
      float mn = fmaxf(m_st, m0a);
      float alpha = exp2f(m_st - mn);
      m_st = mn;
      // ---- P = exp2(S - m) in place; per-lane partial sum; rescale O ----
      float rs = 0.f;
#pragma unroll
      for (int nf = 0; nf < 4; nf++)
#pragma unroll
        for (int reg = 0; reg < 4; reg++) {
          float p = exp2f(s[nf][reg] - m_st);
          s[nf][reg] = p;
          rs += p;
        }
      l_ln = l_ln * alpha + rs;
#pragma unroll
      for (int nfh = 0; nfh < 4; nfh++)
#pragma unroll
        for (int reg = 0; reg < 4; reg++) o[nfh][reg] *= alpha;
      // ---- pack P lane-locally (pi layout) and PV ----
#pragma unroll
      for (int ks = 0; ks < 2; ks++) {
        union { unsigned u[4]; short8 v; } pb;
        asm("v_cvt_pk_bf16_f32 %0, %1, %2" : "=v"(pb.u[0]) : "v"(s[2 * ks][0]), "v"(s[2 * ks][1]));
        asm("v_cvt_pk_bf16_f32 %0, %1, %2" : "=v"(pb.u[1]) : "v"(s[2 * ks][2]), "v"(s[2 * ks][3]));
        asm("v_cvt_pk_bf16_f32 %0, %1, %2" : "=v"(pb.u[2]) : "v"(s[2 * ks + 1][0]), "v"(s[2 * ks + 1][1]));
        asm("v_cvt_pk_bf16_f32 %0, %1, %2" : "=v"(pb.u[3]) : "v"(s[2 * ks + 1][2]), "v"(s[2 * ks + 1][3]));
        __builtin_amdgcn_s_setprio(1);
#pragma unroll
        for (int nfh = 0; nfh < 4; nfh++)
          o[nfh] = MFMA16(vf[ks][nfh], pb.v, o[nfh]);
        __builtin_amdgcn_s_setprio(0);
      }
    }
    // ---- finalize l (deferred reduction) ----
    {
      float s0 = l_ln;
      s0 += __shfl_xor(s0, 16);
      s0 += __shfl_xor(s0, 32);
      l_ln = s0;
    }
    // ---- cross-wave merge: store [q][h], q = wq*16+r, h = nfh*16+g*4+reg ----
    __syncthreads();   // also protects O_l reuse across qi
#pragma unroll
    for (int nfh = 0; nfh < 4; nfh++)
      *(f32x4*)&O_l[wkv][wq * 16 + r][nfh * 16 + g * 4] = o[nfh];
    if (g == 0) {
      st_l[wkv][wq * 16 + r][0] = m_st;
      st_l[wkv][wq * 16 + r][1] = l_ln;
    }
    __syncthreads();
    {
      int row = tid >> 4, cg = tid & 15;   // row = q (0..31), h = cg*4..+3
      float mw[4], lw[4];
#pragma unroll
      for (int ww = 0; ww < 4; ww++) {
        mw[ww] = st_l[ww][row][0];
        lw[ww] = st_l[ww][row][1];
      }
      float mstar = fmaxf(fmaxf(mw[0], mw[1]), fmaxf(mw[2], mw[3]));
      float sc[4], lstar = 0.f;
#pragma unroll
      for (int ww = 0; ww < 4; ww++) { sc[ww] = exp2f(mw[ww] - mstar); lstar += sc[ww] * lw[ww]; }
      float inv = 1.0f / lstar;
      f32x4 a0 = (f32x4){0.f, 0.f, 0.f, 0.f};
#pragma unroll
      for (int ww = 0; ww < 4; ww++) {
        f32x4 v0 = *(f32x4*)&O_l[ww][row][cg * 4];
#pragma unroll
        for (int e = 0; e < 4; e++) a0[e] += sc[ww] * v0[e];
      }
      float4v o0;
#pragma unroll
      for (int e = 0; e < 4; e++) o0[e] = a0[e] * inv;
      *(float4v*)&out[((size_t)b * 4096 + qabs + row) * 64 + cg * 4] = o0;
    }
    __syncthreads();
  }
}

// ---------------------------------------------------------------------------
extern "C" void kernel_launch(void* const* d_in, const int* in_sizes, int n_in,
                              void* d_out, int out_size, void* d_ws, size_t ws_size,
                              hipStream_t stream) {
  (void)in_sizes; (void)n_in; (void)out_size; (void)ws_size;
  const float* x  = (const float*)d_in[0];
  const float* Wk = (const float*)d_in[1];
  const float* Wq = (const float*)d_in[2];
  const float* Wv = (const float*)d_in[3];
  float* out = (float*)d_out;
  char* ws = (char*)d_ws;

  unsigned short* Wt = (unsigned short*)ws;                       // 384KB
  unsigned short* Kb = (unsigned short*)(ws + (512u << 10));      // 2MB
  unsigned short* Qb = (unsigned short*)(ws + (512u << 10) + (2u << 20));
  unsigned short* Vt = (unsigned short*)(ws + (512u << 10) + (4u << 20));

  wtrans_kernel<<<48, 256, 0, stream>>>(Wk, Wq, Wv, Wt);
  proj_kernel<<<512, 256, 0, stream>>>(x, Wt, Kb, Qb, Vt);
  attn_kernel<<<256, 512, 0, stream>>>(Kb, Qb, Vt, out);
}

// Round 8
// 62.958 us; speedup vs baseline: 1.4775x; 1.4775x over previous
//
#include <hip/hip_runtime.h>
#include <hip/hip_bf16.h>

typedef short short8 __attribute__((ext_vector_type(8)));
typedef short short4v __attribute__((ext_vector_type(4)));
typedef float float4v __attribute__((ext_vector_type(4)));
typedef float f32x4 __attribute__((ext_vector_type(4)));

#define NEG_HUGE (-1e30f)
#define QK_SCALE 0.1803368801111204f  /* 0.125 * log2(e) */

__device__ __forceinline__ unsigned short f2bf(float f) {
  union { __hip_bfloat16 h; unsigned short u; } c;
  c.h = __float2bfloat16(f);
  return c.u;
}

#define MFMA16(a, b, c) __builtin_amdgcn_mfma_f32_16x16x32_bf16((a), (b), (c), 0, 0, 0)

// ---------------------------------------------------------------------------
// Kernel 0: W [1024][64] fp32 (x3) -> Wt [3][64][1024] bf16 (transposed).
// Wq additionally scaled by 0.125*log2(e) so attn works in exp2 domain.
// ---------------------------------------------------------------------------
__global__ __launch_bounds__(256) void wtrans_kernel(
    const float* __restrict__ Wk, const float* __restrict__ Wq,
    const float* __restrict__ Wv, unsigned short* __restrict__ Wt) {
  int mat = blockIdx.x >> 4, kb = blockIdx.x & 15;
  const float* W = (mat == 0) ? Wk : ((mat == 1) ? Wq : Wv);
  float qscale = (mat == 1) ? QK_SCALE : 1.0f;
  __shared__ float tile[64][65];
  int tid = threadIdx.x;
  int n = tid & 63, k0 = tid >> 6;
#pragma unroll
  for (int i = 0; i < 16; i++) {
    int k = i * 4 + k0;
    tile[k][n] = W[(kb * 64 + k) * 64 + n];
  }
  __syncthreads();
  int n2 = tid >> 2, c = tid & 3;
  unsigned short tmp[16];
#pragma unroll
  for (int j = 0; j < 16; j++) tmp[j] = f2bf(tile[c * 16 + j][n2] * qscale);
  unsigned short* dst = Wt + (mat * 64 + n2) * 1024 + kb * 64 + c * 16;
  *(short8*)dst = *(short8*)tmp;
  *(short8*)(dst + 8) = *(short8*)(tmp + 8);
}

// ---------------------------------------------------------------------------
// Kernel 1: projection. x[16384][1024] fp32 @ Wt[3][64][1024] bf16
//   -> Kb/Qb [16384][64] bf16 (row-major),
//      Vt [4][64][4096] bf16 transposed with per-64-block kv permutation
//      sigma(kv) = (nf>>1)*32 + g*8 + (nf&1)*4 + reg  (nf=(kv>>4)&3,
//      g=(kv>>2)&3, reg=kv&3) so attn PV B-fragments are lane-local.
// ---------------------------------------------------------------------------
__global__ __launch_bounds__(256, 4) void proj_kernel(
    const float* __restrict__ x, const unsigned short* __restrict__ Wt,
    unsigned short* __restrict__ Kb, unsigned short* __restrict__ Qb,
    unsigned short* __restrict__ Vt) {
  __shared__ unsigned short x_lds[32][40];
  __shared__ unsigned short w_lds[192][40];
  int tid = threadIdx.x;
  int w = tid >> 6, lane = tid & 63;
  int wm = w & 1, wn = w >> 1;
  int g = lane >> 4, r = lane & 15;
  int row0 = blockIdx.x * 32;

  int xr = tid >> 3, c4 = tid & 7;
  const float* xp = &x[(size_t)(row0 + xr) * 1024 + c4 * 4];

  f32x4 acc[6];
#pragma unroll
  for (int nf = 0; nf < 6; nf++) acc[nf] = (f32x4){0.f, 0.f, 0.f, 0.f};

  float4v xv = *(const float4v*)xp;
  short8 wv[3];
#pragma unroll
  for (int i = 0; i < 3; i++) {
    int idx = tid + i * 256;
    int wr = idx >> 2, c = idx & 3;
    wv[i] = *(const short8*)&Wt[wr * 1024 + c * 8];
  }

  for (int k0 = 0; k0 < 1024; k0 += 32) {
    {
      unsigned short t4[4];
      t4[0] = f2bf(xv[0]); t4[1] = f2bf(xv[1]); t4[2] = f2bf(xv[2]); t4[3] = f2bf(xv[3]);
      *(short4v*)&x_lds[xr][c4 * 4] = *(short4v*)t4;
    }
#pragma unroll
    for (int i = 0; i < 3; i++) {
      int idx = tid + i * 256;
      int wr = idx >> 2, c = idx & 3;
      *(short8*)&w_lds[wr][c * 8] = wv[i];
    }
    if (k0 + 32 < 1024) {
      xv = *(const float4v*)(xp + k0 + 32);
#pragma unroll
      for (int i = 0; i < 3; i++) {
        int idx = tid + i * 256;
        int wr = idx >> 2, c = idx & 3;
        wv[i] = *(const short8*)&Wt[wr * 1024 + k0 + 32 + c * 8];
      }
    }
    __syncthreads();
    short8 a = *(short8*)&x_lds[wm * 16 + r][g * 8];
#pragma unroll
    for (int nf = 0; nf < 6; nf++) {
      short8 bf = *(short8*)&w_lds[wn * 96 + nf * 16 + r][g * 8];
      acc[nf] = MFMA16(a, bf, acc[nf]);
    }
    __syncthreads();
  }
#pragma unroll
  for (int nf = 0; nf < 6; nf++) {
    int col = wn * 96 + nf * 16 + r;
    if (col < 128) {
      int mat = col >> 6, h = col & 63;
      unsigned short* dst = (mat == 0) ? Kb : Qb;
#pragma unroll
      for (int reg = 0; reg < 4; reg++) {
        int grow = row0 + wm * 16 + g * 4 + reg;
        dst[(size_t)grow * 64 + h] = f2bf(acc[nf][reg]);
      }
    } else {
      int h = col & 63;
      int grow0 = row0 + wm * 16 + g * 4;
      unsigned short t4[4];
#pragma unroll
      for (int reg = 0; reg < 4; reg++) t4[reg] = f2bf(acc[nf][reg]);
      // sigma permutation within the 64-row block (reg stays contiguous)
      int kv6 = grow0 & 63;
      int nfb = (kv6 >> 4) & 3, gb = (kv6 >> 2) & 3;
      int s0 = (nfb >> 1) * 32 + gb * 8 + (nfb & 1) * 4;
      size_t off = ((size_t)(grow0 >> 12) * 64 + h) * 4096 +
                   ((size_t)(grow0 & 4095) & ~(size_t)63) + s0;
      *(short4v*)&Vt[off] = *(short4v*)t4;
    }
  }
}

// ---------------------------------------------------------------------------
// Kernel 2: causal flash attention v8 (= v6 loop + colocation-balanced qt).
// grid 512, 256 thr = 4 waves kv-split (t%4==w), 32-row q-tile.
// Blocks bi and bi+256 co-reside on the same CU (observed round-robin
// dispatch); qt = (iq<64) ? 64+iq : 127-iq makes each colocated pair's
// ntiles sum exactly 65 -> uniform per-CU work, heavy blocks dispatched
// first. Swapped QK^T + swapped PV with pi-permuted V; P in registers.
// V loads issued AFTER QK^T so their latency hides under softmax.
// ---------------------------------------------------------------------------
__global__ __launch_bounds__(256, 3) void attn_kernel(
    const unsigned short* __restrict__ Kb, const unsigned short* __restrict__ Qb,
    const unsigned short* __restrict__ VtB, float* __restrict__ out) {
  __shared__ float O_l[4][32][68];
  __shared__ float st_l[4][32][2];
  int tid = threadIdx.x;
  int w = tid >> 6, lane = tid & 63;
  int g = lane >> 4, r = lane & 15;
  int bi = blockIdx.x;
  int b = bi & 3, iq = bi >> 2;           // iq 0..127
  int qt = (iq < 64) ? (64 + iq) : (127 - iq);
  int qabs = qt * 32;
  const unsigned short* Kp = Kb + (size_t)b * 4096 * 64;
  const unsigned short* Qp = Qb + (size_t)b * 4096 * 64;
  const unsigned short* Vp = VtB + (size_t)b * 64 * 4096;

  // Q B-operand frags: B[q=mf*16+r][k=h=ks*32+g*8+j]
  short8 qa[2][2];
#pragma unroll
  for (int mf = 0; mf < 2; mf++)
#pragma unroll
    for (int ks = 0; ks < 2; ks++)
      qa[mf][ks] = *(const short8*)&Qp[(size_t)(qabs + mf * 16 + r) * 64 + ks * 32 + g * 8];

  float m_st[2] = {NEG_HUGE, NEG_HUGE};
  float l_ln[2] = {0.f, 0.f};        // per-lane partial row sums
  f32x4 o[4][2];                      // o[nfh][mf]
#pragma unroll
  for (int nfh = 0; nfh < 4; nfh++)
#pragma unroll
    for (int mf = 0; mf < 2; mf++) o[nfh][mf] = (f32x4){0.f, 0.f, 0.f, 0.f};

  int ntiles = (qabs >> 6) + 1;
  for (int t = w; t < ntiles; t += 4) {
    int kvb = t << 6;
    // ---- S^T = K Q^T, K loaded JIT per ks-half ----
    f32x4 s[4][2];
#pragma unroll
    for (int nf = 0; nf < 4; nf++)
#pragma unroll
      for (int mf = 0; mf < 2; mf++) s[nf][mf] = (f32x4){0.f, 0.f, 0.f, 0.f};
#pragma unroll
    for (int ks = 0; ks < 2; ks++) {
      short8 kf[4];
#pragma unroll
      for (int nf = 0; nf < 4; nf++)
        kf[nf] = *(const short8*)&Kp[(size_t)(kvb + nf * 16 + r) * 64 + ks * 32 + g * 8];
#pragma unroll
      for (int nf = 0; nf < 4; nf++) {
        s[nf][0] = MFMA16(kf[nf], qa[0][ks], s[nf][0]);
        s[nf][1] = MFMA16(kf[nf], qa[1][ks], s[nf][1]);
      }
    }
    // ---- V A-fragments issued here: latency hides under softmax ----
    short8 vf[2][4];
#pragma unroll
    for (int ks = 0; ks < 2; ks++)
#pragma unroll
      for (int nfh = 0; nfh < 4; nfh++)
        vf[ks][nfh] = *(const short8*)&Vp[(size_t)(nfh * 16 + r) * 4096 + kvb + ks * 32 + g * 8];
    // ---- causal mask (final tile only) ----
    if (kvb + 63 > qabs) {
#pragma unroll
      for (int mf = 0; mf < 2; mf++) {
        int q = qabs + mf * 16 + r;
#pragma unroll
        for (int nf = 0; nf < 4; nf++)
#pragma unroll
          for (int reg = 0; reg < 4; reg++) {
            int kv = kvb + nf * 16 + g * 4 + reg;
            if (kv > q) s[nf][mf][reg] = NEG_HUGE;
          }
      }
    }
    // ---- row max (in-lane 16 + xor16/xor32), alpha ----
    float alpha[2];
#pragma unroll
    for (int mf = 0; mf < 2; mf++) {
      float m0 = fmaxf(fmaxf(fmaxf(s[0][mf][0], s[0][mf][1]), fmaxf(s[0][mf][2], s[0][mf][3])),
                       fmaxf(fmaxf(s[1][mf][0], s[1][mf][1]), fmaxf(s[1][mf][2], s[1][mf][3])));
      float m1 = fmaxf(fmaxf(fmaxf(s[2][mf][0], s[2][mf][1]), fmaxf(s[2][mf][2], s[2][mf][3])),
                       fmaxf(fmaxf(s[3][mf][0], s[3][mf][1]), fmaxf(s[3][mf][2], s[3][mf][3])));
      float m0a = fmaxf(m0, m1);
      m0a = fmaxf(m0a, __shfl_xor(m0a, 16));
      m0a = fmaxf(m0a, __shfl_xor(m0a, 32));
      float mn = fmaxf(m_st[mf], m0a);
      alpha[mf] = exp2f(m_st[mf] - mn);
      m_st[mf] = mn;
    }
    // ---- P = exp2(S - m) in-place; per-lane partial sums; rescale O ----
#pragma unroll
    for (int mf = 0; mf < 2; mf++) {
      float rs = 0.f;
#pragma unroll
      for (int nf = 0; nf < 4; nf++)
#pragma unroll
        for (int reg = 0; reg < 4; reg++) {
          float p = exp2f(s[nf][mf][reg] - m_st[mf]);
          s[nf][mf][reg] = p;
          rs += p;
        }
      l_ln[mf] = l_ln[mf] * alpha[mf] + rs;
#pragma unroll
      for (int nfh = 0; nfh < 4; nfh++)
#pragma unroll
        for (int reg = 0; reg < 4; reg++) o[nfh][mf][reg] *= alpha[mf];
    }
    // ---- pack P lane-locally (pi layout) and PV ----
#pragma unroll
    for (int ks = 0; ks < 2; ks++)
#pragma unroll
      for (int mf = 0; mf < 2; mf++) {
        union { unsigned u[4]; short8 v; } pb;
        asm("v_cvt_pk_bf16_f32 %0, %1, %2" : "=v"(pb.u[0]) : "v"(s[2 * ks][mf][0]), "v"(s[2 * ks][mf][1]));
        asm("v_cvt_pk_bf16_f32 %0, %1, %2" : "=v"(pb.u[1]) : "v"(s[2 * ks][mf][2]), "v"(s[2 * ks][mf][3]));
        asm("v_cvt_pk_bf16_f32 %0, %1, %2" : "=v"(pb.u[2]) : "v"(s[2 * ks + 1][mf][0]), "v"(s[2 * ks + 1][mf][1]));
        asm("v_cvt_pk_bf16_f32 %0, %1, %2" : "=v"(pb.u[3]) : "v"(s[2 * ks + 1][mf][2]), "v"(s[2 * ks + 1][mf][3]));
#pragma unroll
        for (int nfh = 0; nfh < 4; nfh++)
          o[nfh][mf] = MFMA16(vf[ks][nfh], pb.v, o[nfh][mf]);
      }
  }
  // ---- finalize l (deferred reduction) ----
#pragma unroll
  for (int mf = 0; mf < 2; mf++) {
    float s0 = l_ln[mf];
    s0 += __shfl_xor(s0, 16);
    s0 += __shfl_xor(s0, 32);
    l_ln[mf] = s0;
  }
  // ---- cross-wave merge: store [q][h] (q = mf*16+r, h = nfh*16+g*4+reg) ----
  __syncthreads();
#pragma unroll
  for (int nfh = 0; nfh < 4; nfh++)
#pragma unroll
    for (int mf = 0; mf < 2; mf++)
      *(f32x4*)&O_l[w][mf * 16 + r][nfh * 16 + g * 4] = o[nfh][mf];
  if (g == 0) {
#pragma unroll
    for (int mf = 0; mf < 2; mf++) {
      st_l[w][mf * 16 + r][0] = m_st[mf];
      st_l[w][mf * 16 + r][1] = l_ln[mf];
    }
  }
  __syncthreads();
  {
    int row = tid >> 3, cg = tid & 7;   // row = q (0..31), cg*8 = h block
    float mw[4], lw[4];
#pragma unroll
    for (int ww = 0; ww < 4; ww++) {
      mw[ww] = st_l[ww][row][0];
      lw[ww] = st_l[ww][row][1];
    }
    float mstar = fmaxf(fmaxf(mw[0], mw[1]), fmaxf(mw[2], mw[3]));
    float sc[4], lstar = 0.f;
#pragma unroll
    for (int ww = 0; ww < 4; ww++) { sc[ww] = exp2f(mw[ww] - mstar); lstar += sc[ww] * lw[ww]; }
    float inv = 1.0f / lstar;
    float a0[8];
#pragma unroll
    for (int cc = 0; cc < 8; cc++) a0[cc] = 0.f;
#pragma unroll
    for (int ww = 0; ww < 4; ww++) {
      f32x4 v0 = *(f32x4*)&O_l[ww][row][cg * 8];
      f32x4 v1 = *(f32x4*)&O_l[ww][row][cg * 8 + 4];
#pragma unroll
      for (int e = 0; e < 4; e++) { a0[e] += sc[ww] * v0[e]; a0[4 + e] += sc[ww] * v1[e]; }
    }
    float4v o0, o1;
#pragma unroll
    for (int e = 0; e < 4; e++) { o0[e] = a0[e] * inv; o1[e] = a0[4 + e] * inv; }
    float* op = &out[((size_t)b * 4096 + qabs + row) * 64 + cg * 8];
    *(float4v*)op = o0;
    *(float4v*)(op + 4) = o1;
  }
}

// ---------------------------------------------------------------------------
extern "C" void kernel_launch(void* const* d_in, const int* in_sizes, int n_in,
                              void* d_out, int out_size, void* d_ws, size_t ws_size,
                              hipStream_t stream) {
  (void)in_sizes; (void)n_in; (void)out_size; (void)ws_size;
  const float* x  = (const float*)d_in[0];
  const float* Wk = (const float*)d_in[1];
  const float* Wq = (const float*)d_in[2];
  const float* Wv = (const float*)d_in[3];
  float* out = (float*)d_out;
  char* ws = (char*)d_ws;

  unsigned short* Wt = (unsigned short*)ws;                       // 384KB
  unsigned short* Kb = (unsigned short*)(ws + (512u << 10));      // 2MB
  unsigned short* Qb = (unsigned short*)(ws + (512u << 10) + (2u << 20));
  unsigned short* Vt = (unsigned short*)(ws + (512u << 10) + (4u << 20));

  wtrans_kernel<<<48, 256, 0, stream>>>(Wk, Wq, Wv, Wt);
  proj_kernel<<<512, 256, 0, stream>>>(x, Wt, Kb, Qb, Vt);
  attn_kernel<<<512, 256, 0, stream>>>(Kb, Qb, Vt, out);
}

// Round 9
// 61.880 us; speedup vs baseline: 1.5033x; 1.0174x over previous
//
#include <hip/hip_runtime.h>
#include <hip/hip_bf16.h>

typedef short short8 __attribute__((ext_vector_type(8)));
typedef short short4v __attribute__((ext_vector_type(4)));
typedef float float4v __attribute__((ext_vector_type(4)));
typedef float f32x4 __attribute__((ext_vector_type(4)));

#define NEG_HUGE (-1e30f)
#define QK_SCALE 0.1803368801111204f  /* 0.125 * log2(e) */

__device__ __forceinline__ unsigned short f2bf(float f) {
  union { __hip_bfloat16 h; unsigned short u; } c;
  c.h = __float2bfloat16(f);
  return c.u;
}

#define MFMA16(a, b, c) __builtin_amdgcn_mfma_f32_16x16x32_bf16((a), (b), (c), 0, 0, 0)

// ---------------------------------------------------------------------------
// Kernel 0: W [1024][64] fp32 (x3) -> Wt [3][64][1024] bf16 (transposed).
// Wq additionally scaled by 0.125*log2(e) so attn works in exp2 domain.
// ---------------------------------------------------------------------------
__global__ __launch_bounds__(256) void wtrans_kernel(
    const float* __restrict__ Wk, const float* __restrict__ Wq,
    const float* __restrict__ Wv, unsigned short* __restrict__ Wt) {
  int mat = blockIdx.x >> 4, kb = blockIdx.x & 15;
  const float* W = (mat == 0) ? Wk : ((mat == 1) ? Wq : Wv);
  float qscale = (mat == 1) ? QK_SCALE : 1.0f;
  __shared__ float tile[64][65];
  int tid = threadIdx.x;
  int n = tid & 63, k0 = tid >> 6;
#pragma unroll
  for (int i = 0; i < 16; i++) {
    int k = i * 4 + k0;
    tile[k][n] = W[(kb * 64 + k) * 64 + n];
  }
  __syncthreads();
  int n2 = tid >> 2, c = tid & 3;
  unsigned short tmp[16];
#pragma unroll
  for (int j = 0; j < 16; j++) tmp[j] = f2bf(tile[c * 16 + j][n2] * qscale);
  unsigned short* dst = Wt + (mat * 64 + n2) * 1024 + kb * 64 + c * 16;
  *(short8*)dst = *(short8*)tmp;
  *(short8*)(dst + 8) = *(short8*)(tmp + 8);
}

// ---------------------------------------------------------------------------
// Kernel 1: projection v3 (2-phase pipeline). x[16384][1024] fp32 @
// Wt[3][64][1024] bf16 -> Kb/Qb [16384][64] bf16, Vt [4][64][4096] bf16
// (sigma-permuted, see attn). BM=32, BK=64, 4 waves (wm 0..1 x wn 0..1).
// Double-buffered LDS, reg prefetch of t+1, ONE barrier per iteration.
// LDS pad 68 shorts (136B stride) -> b128 frag reads ~2-way (free).
// ---------------------------------------------------------------------------
__global__ __launch_bounds__(256, 2) void proj_kernel(
    const float* __restrict__ x, const unsigned short* __restrict__ Wt,
    unsigned short* __restrict__ Kb, unsigned short* __restrict__ Qb,
    unsigned short* __restrict__ Vt) {
  __shared__ unsigned short x_lds[2][32][68];   // 8704 B
  __shared__ unsigned short w_lds[2][192][68];  // 52224 B
  int tid = threadIdx.x;
  int w = tid >> 6, lane = tid & 63;
  int wm = w & 1, wn = w >> 1;
  int g = lane >> 4, r = lane & 15;
  int row0 = blockIdx.x * 32;

  // staging assignment: x -> thread (row, 8-float chunk); W -> 6 short8 chunks
  int xr = tid >> 3, xc8 = tid & 7;
  const float* xp = &x[(size_t)(row0 + xr) * 1024 + xc8 * 8];
  int wr[6], wc8[6];
#pragma unroll
  for (int i = 0; i < 6; i++) {
    int idx = tid + i * 256;
    wr[i] = idx >> 3;
    wc8[i] = idx & 7;
  }

  f32x4 acc[6];
#pragma unroll
  for (int nf = 0; nf < 6; nf++) acc[nf] = (f32x4){0.f, 0.f, 0.f, 0.f};

  float4v xv0, xv1;
  short8 wv[6];

  // load tile 0
  xv0 = *(const float4v*)(xp + 0);
  xv1 = *(const float4v*)(xp + 4);
#pragma unroll
  for (int i = 0; i < 6; i++)
    wv[i] = *(const short8*)&Wt[wr[i] * 1024 + wc8[i] * 8];

  // write tile 0 -> buf 0
  {
    unsigned short t8[8];
    t8[0] = f2bf(xv0[0]); t8[1] = f2bf(xv0[1]); t8[2] = f2bf(xv0[2]); t8[3] = f2bf(xv0[3]);
    t8[4] = f2bf(xv1[0]); t8[5] = f2bf(xv1[1]); t8[6] = f2bf(xv1[2]); t8[7] = f2bf(xv1[3]);
    *(short8*)&x_lds[0][xr][xc8 * 8] = *(short8*)t8;
#pragma unroll
    for (int i = 0; i < 6; i++)
      *(short8*)&w_lds[0][wr[i]][wc8[i] * 8] = wv[i];
  }
  __syncthreads();

  for (int t = 0; t < 16; t++) {
    int cur = t & 1;
    // issue global loads for tile t+1 (consumed at end of this iter)
    if (t < 15) {
      int k0 = (t + 1) * 64;
      xv0 = *(const float4v*)(xp + k0);
      xv1 = *(const float4v*)(xp + k0 + 4);
#pragma unroll
      for (int i = 0; i < 6; i++)
        wv[i] = *(const short8*)&Wt[wr[i] * 1024 + k0 + wc8[i] * 8];
    }
    // compute on buf[cur]
    short8 a0 = *(short8*)&x_lds[cur][wm * 16 + r][g * 8];
    short8 a1 = *(short8*)&x_lds[cur][wm * 16 + r][32 + g * 8];
#pragma unroll
    for (int nf = 0; nf < 6; nf++) {
      short8 b0 = *(short8*)&w_lds[cur][wn * 96 + nf * 16 + r][g * 8];
      short8 b1 = *(short8*)&w_lds[cur][wn * 96 + nf * 16 + r][32 + g * 8];
      acc[nf] = MFMA16(a0, b0, acc[nf]);
      acc[nf] = MFMA16(a1, b1, acc[nf]);
    }
    // stage tile t+1 into the other buffer (vmcnt wait auto-inserted)
    if (t < 15) {
      unsigned short t8[8];
      t8[0] = f2bf(xv0[0]); t8[1] = f2bf(xv0[1]); t8[2] = f2bf(xv0[2]); t8[3] = f2bf(xv0[3]);
      t8[4] = f2bf(xv1[0]); t8[5] = f2bf(xv1[1]); t8[6] = f2bf(xv1[2]); t8[7] = f2bf(xv1[3]);
      *(short8*)&x_lds[cur ^ 1][xr][xc8 * 8] = *(short8*)t8;
#pragma unroll
      for (int i = 0; i < 6; i++)
        *(short8*)&w_lds[cur ^ 1][wr[i]][wc8[i] * 8] = wv[i];
    }
    __syncthreads();
  }
  // epilogue: row = row0 + wm*16 + g*4 + reg, col = wn*96 + nf*16 + r
#pragma unroll
  for (int nf = 0; nf < 6; nf++) {
    int col = wn * 96 + nf * 16 + r;
    if (col < 128) {
      int mat = col >> 6, h = col & 63;
      unsigned short* dst = (mat == 0) ? Kb : Qb;
#pragma unroll
      for (int reg = 0; reg < 4; reg++) {
        int grow = row0 + wm * 16 + g * 4 + reg;
        dst[(size_t)grow * 64 + h] = f2bf(acc[nf][reg]);
      }
    } else {
      int h = col & 63;
      int grow0 = row0 + wm * 16 + g * 4;
      unsigned short t4[4];
#pragma unroll
      for (int reg = 0; reg < 4; reg++) t4[reg] = f2bf(acc[nf][reg]);
      // sigma permutation within the 64-row block (reg stays contiguous)
      int kv6 = grow0 & 63;
      int nfb = (kv6 >> 4) & 3, gb = (kv6 >> 2) & 3;
      int s0 = (nfb >> 1) * 32 + gb * 8 + (nfb & 1) * 4;
      size_t off = ((size_t)(grow0 >> 12) * 64 + h) * 4096 +
                   ((size_t)(grow0 & 4095) & ~(size_t)63) + s0;
      *(short4v*)&Vt[off] = *(short4v*)t4;
    }
  }
}

// ---------------------------------------------------------------------------
// Kernel 2: causal flash attention v8 (= v6 loop + colocation-balanced qt).
// grid 512, 256 thr = 4 waves kv-split (t%4==w), 32-row q-tile.
// Blocks bi and bi+256 co-reside on the same CU (observed round-robin
// dispatch); qt = (iq<64) ? 64+iq : 127-iq makes each colocated pair's
// ntiles sum exactly 65 -> uniform per-CU work, heavy blocks dispatched
// first. Swapped QK^T + swapped PV with pi-permuted V; P in registers.
// V loads issued AFTER QK^T so their latency hides under softmax.
// ---------------------------------------------------------------------------
__global__ __launch_bounds__(256, 3) void attn_kernel(
    const unsigned short* __restrict__ Kb, const unsigned short* __restrict__ Qb,
    const unsigned short* __restrict__ VtB, float* __restrict__ out) {
  __shared__ float O_l[4][32][68];
  __shared__ float st_l[4][32][2];
  int tid = threadIdx.x;
  int w = tid >> 6, lane = tid & 63;
  int g = lane >> 4, r = lane & 15;
  int bi = blockIdx.x;
  int b = bi & 3, iq = bi >> 2;           // iq 0..127
  int qt = (iq < 64) ? (64 + iq) : (127 - iq);
  int qabs = qt * 32;
  const unsigned short* Kp = Kb + (size_t)b * 4096 * 64;
  const unsigned short* Qp = Qb + (size_t)b * 4096 * 64;
  const unsigned short* Vp = VtB + (size_t)b * 64 * 4096;

  // Q B-operand frags: B[q=mf*16+r][k=h=ks*32+g*8+j]
  short8 qa[2][2];
#pragma unroll
  for (int mf = 0; mf < 2; mf++)
#pragma unroll
    for (int ks = 0; ks < 2; ks++)
      qa[mf][ks] = *(const short8*)&Qp[(size_t)(qabs + mf * 16 + r) * 64 + ks * 32 + g * 8];

  float m_st[2] = {NEG_HUGE, NEG_HUGE};
  float l_ln[2] = {0.f, 0.f};        // per-lane partial row sums
  f32x4 o[4][2];                      // o[nfh][mf]
#pragma unroll
  for (int nfh = 0; nfh < 4; nfh++)
#pragma unroll
    for (int mf = 0; mf < 2; mf++) o[nfh][mf] = (f32x4){0.f, 0.f, 0.f, 0.f};

  int ntiles = (qabs >> 6) + 1;
  for (int t = w; t < ntiles; t += 4) {
    int kvb = t << 6;
    // ---- S^T = K Q^T, K loaded JIT per ks-half ----
    f32x4 s[4][2];
#pragma unroll
    for (int nf = 0; nf < 4; nf++)
#pragma unroll
      for (int mf = 0; mf < 2; mf++) s[nf][mf] = (f32x4){0.f, 0.f, 0.f, 0.f};
#pragma unroll
    for (int ks = 0; ks < 2; ks++) {
      short8 kf[4];
#pragma unroll
      for (int nf = 0; nf < 4; nf++)
        kf[nf] = *(const short8*)&Kp[(size_t)(kvb + nf * 16 + r) * 64 + ks * 32 + g * 8];
#pragma unroll
      for (int nf = 0; nf < 4; nf++) {
        s[nf][0] = MFMA16(kf[nf], qa[0][ks], s[nf][0]);
        s[nf][1] = MFMA16(kf[nf], qa[1][ks], s[nf][1]);
      }
    }
    // ---- V A-fragments issued here: latency hides under softmax ----
    short8 vf[2][4];
#pragma unroll
    for (int ks = 0; ks < 2; ks++)
#pragma unroll
      for (int nfh = 0; nfh < 4; nfh++)
        vf[ks][nfh] = *(const short8*)&Vp[(size_t)(nfh * 16 + r) * 4096 + kvb + ks * 32 + g * 8];
    // ---- causal mask (final tile only) ----
    if (kvb + 63 > qabs) {
#pragma unroll
      for (int mf = 0; mf < 2; mf++) {
        int q = qabs + mf * 16 + r;
#pragma unroll
        for (int nf = 0; nf < 4; nf++)
#pragma unroll
          for (int reg = 0; reg < 4; reg++) {
            int kv = kvb + nf * 16 + g * 4 + reg;
            if (kv > q) s[nf][mf][reg] = NEG_HUGE;
          }
      }
    }
    // ---- row max (in-lane 16 + xor16/xor32), alpha ----
    float alpha[2];
#pragma unroll
    for (int mf = 0; mf < 2; mf++) {
      float m0 = fmaxf(fmaxf(fmaxf(s[0][mf][0], s[0][mf][1]), fmaxf(s[0][mf][2], s[0][mf][3])),
                       fmaxf(fmaxf(s[1][mf][0], s[1][mf][1]), fmaxf(s[1][mf][2], s[1][mf][3])));
      float m1 = fmaxf(fmaxf(fmaxf(s[2][mf][0], s[2][mf][1]), fmaxf(s[2][mf][2], s[2][mf][3])),
                       fmaxf(fmaxf(s[3][mf][0], s[3][mf][1]), fmaxf(s[3][mf][2], s[3][mf][3])));
      float m0a = fmaxf(m0, m1);
      m0a = fmaxf(m0a, __shfl_xor(m0a, 16));
      m0a = fmaxf(m0a, __shfl_xor(m0a, 32));
      float mn = fmaxf(m_st[mf], m0a);
      alpha[mf] = exp2f(m_st[mf] - mn);
      m_st[mf] = mn;
    }
    // ---- P = exp2(S - m) in-place; per-lane partial sums; rescale O ----
#pragma unroll
    for (int mf = 0; mf < 2; mf++) {
      float rs = 0.f;
#pragma unroll
      for (int nf = 0; nf < 4; nf++)
#pragma unroll
        for (int reg = 0; reg < 4; reg++) {
          float p = exp2f(s[nf][mf][reg] - m_st[mf]);
          s[nf][mf][reg] = p;
          rs += p;
        }
      l_ln[mf] = l_ln[mf] * alpha[mf] + rs;
#pragma unroll
      for (int nfh = 0; nfh < 4; nfh++)
#pragma unroll
        for (int reg = 0; reg < 4; reg++) o[nfh][mf][reg] *= alpha[mf];
    }
    // ---- pack P lane-locally (pi layout) and PV ----
#pragma unroll
    for (int ks = 0; ks < 2; ks++)
#pragma unroll
      for (int mf = 0; mf < 2; mf++) {
        union { unsigned u[4]; short8 v; } pb;
        asm("v_cvt_pk_bf16_f32 %0, %1, %2" : "=v"(pb.u[0]) : "v"(s[2 * ks][mf][0]), "v"(s[2 * ks][mf][1]));
        asm("v_cvt_pk_bf16_f32 %0, %1, %2" : "=v"(pb.u[1]) : "v"(s[2 * ks][mf][2]), "v"(s[2 * ks][mf][3]));
        asm("v_cvt_pk_bf16_f32 %0, %1, %2" : "=v"(pb.u[2]) : "v"(s[2 * ks + 1][mf][0]), "v"(s[2 * ks + 1][mf][1]));
        asm("v_cvt_pk_bf16_f32 %0, %1, %2" : "=v"(pb.u[3]) : "v"(s[2 * ks + 1][mf][2]), "v"(s[2 * ks + 1][mf][3]));
#pragma unroll
        for (int nfh = 0; nfh < 4; nfh++)
          o[nfh][mf] = MFMA16(vf[ks][nfh], pb.v, o[nfh][mf]);
      }
  }
  // ---- finalize l (deferred reduction) ----
#pragma unroll
  for (int mf = 0; mf < 2; mf++) {
    float s0 = l_ln[mf];
    s0 += __shfl_xor(s0, 16);
    s0 += __shfl_xor(s0, 32);
    l_ln[mf] = s0;
  }
  // ---- cross-wave merge: store [q][h] (q = mf*16+r, h = nfh*16+g*4+reg) ----
  __syncthreads();
#pragma unroll
  for (int nfh = 0; nfh < 4; nfh++)
#pragma unroll
    for (int mf = 0; mf < 2; mf++)
      *(f32x4*)&O_l[w][mf * 16 + r][nfh * 16 + g * 4] = o[nfh][mf];
  if (g == 0) {
#pragma unroll
    for (int mf = 0; mf < 2; mf++) {
      st_l[w][mf * 16 + r][0] = m_st[mf];
      st_l[w][mf * 16 + r][1] = l_ln[mf];
    }
  }
  __syncthreads();
  {
    int row = tid >> 3, cg = tid & 7;   // row = q (0..31), cg*8 = h block
    float mw[4], lw[4];
#pragma unroll
    for (int ww = 0; ww < 4; ww++) {
      mw[ww] = st_l[ww][row][0];
      lw[ww] = st_l[ww][row][1];
    }
    float mstar = fmaxf(fmaxf(mw[0], mw[1]), fmaxf(mw[2], mw[3]));
    float sc[4], lstar = 0.f;
#pragma unroll
    for (int ww = 0; ww < 4; ww++) { sc[ww] = exp2f(mw[ww] - mstar); lstar += sc[ww] * lw[ww]; }
    float inv = 1.0f / lstar;
    float a0[8];
#pragma unroll
    for (int cc = 0; cc < 8; cc++) a0[cc] = 0.f;
#pragma unroll
    for (int ww = 0; ww < 4; ww++) {
      f32x4 v0 = *(f32x4*)&O_l[ww][row][cg * 8];
      f32x4 v1 = *(f32x4*)&O_l[ww][row][cg * 8 + 4];
#pragma unroll
      for (int e = 0; e < 4; e++) { a0[e] += sc[ww] * v0[e]; a0[4 + e] += sc[ww] * v1[e]; }
    }
    float4v o0, o1;
#pragma unroll
    for (int e = 0; e < 4; e++) { o0[e] = a0[e] * inv; o1[e] = a0[4 + e] * inv; }
    float* op = &out[((size_t)b * 4096 + qabs + row) * 64 + cg * 8];
    *(float4v*)op = o0;
    *(float4v*)(op + 4) = o1;
  }
}

// ---------------------------------------------------------------------------
extern "C" void kernel_launch(void* const* d_in, const int* in_sizes, int n_in,
                              void* d_out, int out_size, void* d_ws, size_t ws_size,
                              hipStream_t stream) {
  (void)in_sizes; (void)n_in; (void)out_size; (void)ws_size;
  const float* x  = (const float*)d_in[0];
  const float* Wk = (const float*)d_in[1];
  const float* Wq = (const float*)d_in[2];
  const float* Wv = (const float*)d_in[3];
  float* out = (float*)d_out;
  char* ws = (char*)d_ws;

  unsigned short* Wt = (unsigned short*)ws;                       // 384KB
  unsigned short* Kb = (unsigned short*)(ws + (512u << 10));      // 2MB
  unsigned short* Qb = (unsigned short*)(ws + (512u << 10) + (2u << 20));
  unsigned short* Vt = (unsigned short*)(ws + (512u << 10) + (4u << 20));

  wtrans_kernel<<<48, 256, 0, stream>>>(Wk, Wq, Wv, Wt);
  proj_kernel<<<512, 256, 0, stream>>>(x, Wt, Kb, Qb, Vt);
  attn_kernel<<<512, 256, 0, stream>>>(Kb, Qb, Vt, out);
}